// Round 13
// baseline (389.975 us; speedup 1.0000x reference)
//
#include <hip/hip_runtime.h>

typedef unsigned long long u64;
typedef unsigned int u32;

#define D_FEAT 32
#define NPB 128            // nodes per bucket
#define BSHIFT 7           // log2(NPB)
#define NB_MAX 1024        // max bucket count supported by scan / LDS arrays
#define NBLK 512           // edge-chunk blocks for count/scatter
#define ABLK 512           // threads per block for count/scatter
#define PAD 16             // pad global bucket counters to 64 B

// ---------- K1: fused count + reserve (vectorized) ----------
__global__ void __launch_bounds__(ABLK)
count_reserve(const int* __restrict__ ei, int* __restrict__ btot,
              int* __restrict__ rel, int E, int NB, int epb) {
    __shared__ int hist[NB_MAX];
    for (int k = threadIdx.x; k < NB; k += blockDim.x) hist[k] = 0;
    __syncthreads();
    const int e0 = blockIdx.x * epb;
    const int e1 = min(E, e0 + epb);
    if (((e0 | e1) & 3) == 0) {
        const int4* s4p = (const int4*)ei;
        for (int q = (e0 >> 2) + threadIdx.x; q < (e1 >> 2); q += blockDim.x) {
            const int4 s4 = s4p[q];
            atomicAdd(&hist[s4.x >> BSHIFT], 1);
            atomicAdd(&hist[s4.y >> BSHIFT], 1);
            atomicAdd(&hist[s4.z >> BSHIFT], 1);
            atomicAdd(&hist[s4.w >> BSHIFT], 1);
        }
    } else {
        for (int e = e0 + threadIdx.x; e < e1; e += blockDim.x)
            atomicAdd(&hist[ei[e] >> BSHIFT], 1);
    }
    __syncthreads();
    for (int k = threadIdx.x; k < NB; k += blockDim.x) {
        const int h = hist[k];
        rel[(size_t)blockIdx.x * NB + k] = h ? atomicAdd(&btot[k * PAD], h) : 0;
    }
}

// ---------- K2: exclusive scan of bucket totals (one block) ----------
__global__ void __launch_bounds__(NB_MAX)
scan_totals(const int* __restrict__ btot, int* __restrict__ bbase, int NB) {
    __shared__ int lds[NB_MAX];
    const int t = threadIdx.x;
    const int v = (t < NB) ? btot[t * PAD] : 0;
    lds[t] = v;
    __syncthreads();
    for (int d = 1; d < NB_MAX; d <<= 1) {
        int tmp = (t >= d) ? lds[t - d] : 0;
        __syncthreads();
        lds[t] += tmp;
        __syncthreads();
    }
    if (t < NB) bbase[t] = lds[t] - v;
    if (t == NB - 1) bbase[NB] = lds[t];    // total = E
}

// ---------- K3: scatter edges into bucket-contiguous slots, LDS cursors ----------
__global__ void __launch_bounds__(ABLK)
bin_scatter(const int* __restrict__ ei, const float* __restrict__ attr,
            const int* __restrict__ rel, const int* __restrict__ bbase,
            u64* __restrict__ dstbuf, int E, int NB, int epb) {
    __shared__ int cur[NB_MAX];
    for (int k = threadIdx.x; k < NB; k += blockDim.x)
        cur[k] = bbase[k] + rel[(size_t)blockIdx.x * NB + k];
    __syncthreads();
    const int e0 = blockIdx.x * epb;
    const int e1 = min(E, e0 + epb);
    if (((e0 | e1 | E) & 3) == 0) {
        const int4* s4p = (const int4*)ei;
        const int4* d4p = (const int4*)(ei + E);
        const float4* a4p = (const float4*)attr;
        for (int q = (e0 >> 2) + threadIdx.x; q < (e1 >> 2); q += blockDim.x) {
            const int4 s4 = s4p[q];
            const int4 d4 = d4p[q];
            const float4 a4 = a4p[q];
            #pragma unroll
            for (int r = 0; r < 4; ++r) {
                const int s = (&s4.x)[r];
                const u32 d = (u32)(&d4.x)[r];
                const u32 a = __float_as_uint((&a4.x)[r]);
                const int pos = atomicAdd(&cur[s >> BSHIFT], 1);
                dstbuf[pos] = ((u64)a << 32) | (d | ((u32)(s & (NPB - 1)) << 20));
            }
        }
    } else {
        for (int e = e0 + threadIdx.x; e < e1; e += blockDim.x) {
            const int s = ei[e];
            const u32 d = (u32)ei[E + e];
            const u32 a = __float_as_uint(attr[e]);
            const int pos = atomicAdd(&cur[s >> BSHIFT], 1);
            dstbuf[pos] = ((u64)a << 32) | (d | ((u32)(s & (NPB - 1)) << 20));
        }
    }
}

// ---------- K4: per-bucket LDS accumulation (no sort) ----------
// One 512-thread block per bucket. 16 x 32-lane units; each unit takes 4
// consecutive edges per iteration: 4 independent x-row loads in flight,
// then 4 ds_add_f32. acc[local][feat]: bank == lane -> conflict-free.
__global__ void __launch_bounds__(512)
accum_gather(const u64* __restrict__ buf, const int* __restrict__ bbase,
             const float* __restrict__ x, float* __restrict__ out, int N) {
    __shared__ float acc[NPB * D_FEAT];   // 16 KB
    const int k = blockIdx.x, t = threadIdx.x;
    for (int i = t; i < NPB * D_FEAT; i += 512) acc[i] = 0.0f;
    __syncthreads();

    const int start = bbase[k], end = bbase[k + 1];
    const int lane = t & 31;              // feature
    const int unit = t >> 5;              // 0..15

    int i = start + unit * 4;
    // stride: 16 units * 4 edges = 64 edges per sweep
    for (; i + 4 <= end; i += 64) {
        const u64 p0 = buf[i], p1 = buf[i + 1], p2 = buf[i + 2], p3 = buf[i + 3];
        const u32 l0 = (u32)p0, l1 = (u32)p1, l2 = (u32)p2, l3 = (u32)p3;
        const float v0 = x[(((size_t)(l0 & 0xFFFFFu)) << 5) + lane];
        const float v1 = x[(((size_t)(l1 & 0xFFFFFu)) << 5) + lane];
        const float v2 = x[(((size_t)(l2 & 0xFFFFFu)) << 5) + lane];
        const float v3 = x[(((size_t)(l3 & 0xFFFFFu)) << 5) + lane];
        const float a0 = __uint_as_float((u32)(p0 >> 32));
        const float a1 = __uint_as_float((u32)(p1 >> 32));
        const float a2 = __uint_as_float((u32)(p2 >> 32));
        const float a3 = __uint_as_float((u32)(p3 >> 32));
        atomicAdd(&acc[(int)((l0 >> 20) & (NPB - 1)) * D_FEAT + lane], a0 * v0);
        atomicAdd(&acc[(int)((l1 >> 20) & (NPB - 1)) * D_FEAT + lane], a1 * v1);
        atomicAdd(&acc[(int)((l2 >> 20) & (NPB - 1)) * D_FEAT + lane], a2 * v2);
        atomicAdd(&acc[(int)((l3 >> 20) & (NPB - 1)) * D_FEAT + lane], a3 * v3);
    }
    // tail (< 4 edges for this unit)
    for (; i < end; ++i) {
        const u64 p = buf[i];
        const u32 lo = (u32)p;
        const float v = x[(((size_t)(lo & 0xFFFFFu)) << 5) + lane];
        const float a = __uint_as_float((u32)(p >> 32));
        atomicAdd(&acc[(int)((lo >> 20) & (NPB - 1)) * D_FEAT + lane], a * v);
    }
    __syncthreads();

    const int node0 = k << BSHIFT;
    const int nelm = (min(NPB, N - node0)) * D_FEAT;
    float* ob = out + ((size_t)node0 << 5);
    for (int idx = t; idx < nelm; idx += 512) ob[idx] = acc[idx];
}

// ---------- fallback (generality): direct atomic scatter ----------
__global__ void fallback_scatter(const int* __restrict__ ei, const float* __restrict__ attr,
                                 const float* __restrict__ x, float* __restrict__ out, int E) {
    const long long total = (long long)E * D_FEAT;
    const long long stride = (long long)gridDim.x * blockDim.x;
    for (long long i = (long long)blockIdx.x * blockDim.x + threadIdx.x; i < total; i += stride) {
        const int e = (int)(i >> 5);
        const int d = (int)(i & 31);
        atomicAdd(&out[((long long)ei[e] << 5) + d],
                  attr[e] * x[((long long)ei[E + e] << 5) + d]);
    }
}

extern "C" void kernel_launch(void* const* d_in, const int* in_sizes, int n_in,
                              void* d_out, int out_size, void* d_ws, size_t ws_size,
                              hipStream_t stream) {
    const int* edge_index = (const int*)d_in[0];    // [2, E] int32
    const float* edge_attr = (const float*)d_in[1]; // [E] f32
    const float* x = (const float*)d_in[2];         // [N, 32] f32
    float* out = (float*)d_out;                     // [N, 32] f32

    const int E = in_sizes[1];
    const int N = in_sizes[2] / D_FEAT;
    const int NB = (N + NPB - 1) >> BSHIFT;

    // Workspace layout (256-B aligned sections)
    char* ws = (char*)d_ws;
    int* btot = (int*)ws;                                              // NB*PAD
    size_t o1 = (((size_t)NB * PAD * 4) + 255) & ~(size_t)255;
    int* bbase = (int*)(ws + o1);                                      // NB+1
    size_t o2 = (o1 + ((size_t)(NB + 1) * 4) + 255) & ~(size_t)255;
    int* rel = (int*)(ws + o2);                                        // NBLK*NB
    size_t o3 = (o2 + ((size_t)NBLK * NB * 4) + 255) & ~(size_t)255;
    u64* bufA = (u64*)(ws + o3);                                       // E
    size_t need = o3 + (size_t)E * 8;

    if (NB > NB_MAX || N > (1 << 20) || need > ws_size) {
        hipMemsetAsync(d_out, 0, (size_t)out_size * sizeof(float), stream);
        long long total = (long long)E * D_FEAT;
        int grid = (int)((total + 255) / 256);
        if (grid > 65536) grid = 65536;
        fallback_scatter<<<grid, 256, 0, stream>>>(edge_index, edge_attr, x, out, E);
        return;
    }

    hipMemsetAsync(btot, 0, (size_t)NB * PAD * 4, stream);

    int epb = (E + NBLK - 1) / NBLK;
    epb = (epb + 3) & ~3;

    count_reserve<<<NBLK, ABLK, 0, stream>>>(edge_index, btot, rel, E, NB, epb);
    scan_totals<<<1, NB_MAX, 0, stream>>>(btot, bbase, NB);
    bin_scatter<<<NBLK, ABLK, 0, stream>>>(edge_index, edge_attr, rel, bbase, bufA, E, NB, epb);
    accum_gather<<<NB, 512, 0, stream>>>(bufA, bbase, x, out, N);
}

// Round 14
// 94.752 us; speedup vs baseline: 4.1157x; 4.1157x over previous
//
#include <hip/hip_runtime.h>

typedef unsigned long long u64;
typedef unsigned int u32;

#define D_FEAT 32
#define NPB 128            // nodes per bucket
#define BSHIFT 7           // log2(NPB)
#define NB_MAX 1024        // max bucket count supported by scan / LDS arrays
#define NBLK 512           // edge-chunk blocks for count/scatter
#define ABLK 512           // threads per block for count/scatter
#define CAP 4096           // max edges per bucket stageable in LDS (avg 2048 here)
#define PAD 16             // pad global bucket counters to 64 B

// ---------- K1: fused count + reserve (vectorized, proven 512x512 shape) ----------
__global__ void __launch_bounds__(ABLK)
count_reserve(const int* __restrict__ ei, int* __restrict__ btot,
              int* __restrict__ rel, int E, int NB, int epb) {
    __shared__ int hist[NB_MAX];
    for (int k = threadIdx.x; k < NB; k += blockDim.x) hist[k] = 0;
    __syncthreads();
    const int e0 = blockIdx.x * epb;
    const int e1 = min(E, e0 + epb);
    if (((e0 | e1) & 3) == 0) {
        const int4* s4p = (const int4*)ei;
        for (int q = (e0 >> 2) + threadIdx.x; q < (e1 >> 2); q += blockDim.x) {
            const int4 s4 = s4p[q];
            atomicAdd(&hist[s4.x >> BSHIFT], 1);
            atomicAdd(&hist[s4.y >> BSHIFT], 1);
            atomicAdd(&hist[s4.z >> BSHIFT], 1);
            atomicAdd(&hist[s4.w >> BSHIFT], 1);
        }
    } else {
        for (int e = e0 + threadIdx.x; e < e1; e += blockDim.x)
            atomicAdd(&hist[ei[e] >> BSHIFT], 1);
    }
    __syncthreads();
    for (int k = threadIdx.x; k < NB; k += blockDim.x) {
        const int h = hist[k];
        rel[(size_t)blockIdx.x * NB + k] = h ? atomicAdd(&btot[k * PAD], h) : 0;
    }
}

// ---------- K2: exclusive scan of bucket totals (one block) ----------
__global__ void __launch_bounds__(NB_MAX)
scan_totals(const int* __restrict__ btot, int* __restrict__ bbase, int NB) {
    __shared__ int lds[NB_MAX];
    const int t = threadIdx.x;
    const int v = (t < NB) ? btot[t * PAD] : 0;
    lds[t] = v;
    __syncthreads();
    for (int d = 1; d < NB_MAX; d <<= 1) {
        int tmp = (t >= d) ? lds[t - d] : 0;
        __syncthreads();
        lds[t] += tmp;
        __syncthreads();
    }
    if (t < NB) bbase[t] = lds[t] - v;
    if (t == NB - 1) bbase[NB] = lds[t];    // total = E
}

// ---------- K3: scatter edges into bucket-contiguous slots, LDS cursors ----------
__global__ void __launch_bounds__(ABLK)
bin_scatter(const int* __restrict__ ei, const float* __restrict__ attr,
            const int* __restrict__ rel, const int* __restrict__ bbase,
            u64* __restrict__ dstbuf, int E, int NB, int epb) {
    __shared__ int cur[NB_MAX];
    for (int k = threadIdx.x; k < NB; k += blockDim.x)
        cur[k] = bbase[k] + rel[(size_t)blockIdx.x * NB + k];
    __syncthreads();
    const int e0 = blockIdx.x * epb;
    const int e1 = min(E, e0 + epb);
    if (((e0 | e1 | E) & 3) == 0) {
        const int4* s4p = (const int4*)ei;
        const int4* d4p = (const int4*)(ei + E);
        const float4* a4p = (const float4*)attr;
        for (int q = (e0 >> 2) + threadIdx.x; q < (e1 >> 2); q += blockDim.x) {
            const int4 s4 = s4p[q];
            const int4 d4 = d4p[q];
            const float4 a4 = a4p[q];
            #pragma unroll
            for (int r = 0; r < 4; ++r) {
                const int s = (&s4.x)[r];
                const u32 d = (u32)(&d4.x)[r];
                const u32 a = __float_as_uint((&a4.x)[r]);
                const int pos = atomicAdd(&cur[s >> BSHIFT], 1);
                dstbuf[pos] = ((u64)a << 32) | (d | ((u32)(s & (NPB - 1)) << 20));
            }
        }
    } else {
        for (int e = e0 + threadIdx.x; e < e1; e += blockDim.x) {
            const int s = ei[e];
            const u32 d = (u32)ei[E + e];
            const u32 a = __float_as_uint(attr[e]);
            const int pos = atomicAdd(&cur[s >> BSHIFT], 1);
            dstbuf[pos] = ((u64)a << 32) | (d | ((u32)(s & (NPB - 1)) << 20));
        }
    }
}

// ---------- K4: per-bucket LDS counting sort A->B + node offsets ----------
__global__ void __launch_bounds__(512)
bucket_sort(const u64* __restrict__ srcbuf, u64* __restrict__ dstbuf,
            const int* __restrict__ bbase, int* __restrict__ node_off, int N, int NB) {
    __shared__ u64 stage[CAP];     // 32 KB
    __shared__ int hist[NPB];
    __shared__ int cur[NPB];
    const int k = blockIdx.x, t = threadIdx.x;
    const int start = bbase[k], end = bbase[k + 1];
    const int cnt = end - start;

    if (t < NPB) hist[t] = 0;
    __syncthreads();

    for (int i = t; i < cnt; i += 512) {
        u64 p = srcbuf[start + i];
        if (i < CAP) stage[i] = p;
        atomicAdd(&hist[(int)(((u32)p >> 20) & (NPB - 1))], 1);
    }
    __syncthreads();

    int orig = (t < NPB) ? hist[t] : 0;
    for (int d = 1; d < NPB; d <<= 1) {
        int tmp = (t >= d && t < NPB) ? hist[t - d] : 0;
        __syncthreads();
        if (t < NPB) hist[t] += tmp;
        __syncthreads();
    }
    if (t < NPB) {
        int excl = hist[t] - orig;
        cur[t] = excl;
        int node = (k << BSHIFT) + t;
        if (node < N) node_off[node] = start + excl;
    }
    if (k == NB - 1 && t == 0) node_off[N] = end;
    __syncthreads();

    for (int i = t; i < cnt; i += 512) {
        u64 p = (i < CAP) ? stage[i] : srcbuf[start + i];
        int local = (int)(((u32)p >> 20) & (NPB - 1));
        int pos = atomicAdd(&cur[local], 1);
        dstbuf[start + pos] = p;
    }
}

// ---------- K5: node-parallel gather, 8 lanes/node, float4, 8-edge unroll ----------
__global__ void __launch_bounds__(256)
csr_gather(const u64* __restrict__ csr, const int* __restrict__ node_off,
           const float* __restrict__ x, float* __restrict__ out, int N) {
    const int gid = (blockIdx.x * 256 + threadIdx.x) >> 3;  // node
    const int l4 = (threadIdx.x & 7) << 2;                  // feature*4
    if (gid >= N) return;
    const int s = node_off[gid], e = node_off[gid + 1];

    float ax = 0.f, ay = 0.f, az = 0.f, aw = 0.f;
    int k = s;
    for (; k + 8 <= e; k += 8) {
        u64 p[8];
        #pragma unroll
        for (int j = 0; j < 8; ++j) p[j] = csr[k + j];
        float4 v[8];
        #pragma unroll
        for (int j = 0; j < 8; ++j)
            v[j] = *(const float4*)&x[(((size_t)((u32)p[j] & 0xFFFFFu)) << 5) + l4];
        #pragma unroll
        for (int j = 0; j < 8; ++j) {
            const float a = __uint_as_float((u32)(p[j] >> 32));
            ax = fmaf(a, v[j].x, ax); ay = fmaf(a, v[j].y, ay);
            az = fmaf(a, v[j].z, az); aw = fmaf(a, v[j].w, aw);
        }
    }
    for (; k + 4 <= e; k += 4) {
        const u64 p0 = csr[k], p1 = csr[k + 1], p2 = csr[k + 2], p3 = csr[k + 3];
        const float4 v0 = *(const float4*)&x[(((size_t)((u32)p0 & 0xFFFFFu)) << 5) + l4];
        const float4 v1 = *(const float4*)&x[(((size_t)((u32)p1 & 0xFFFFFu)) << 5) + l4];
        const float4 v2 = *(const float4*)&x[(((size_t)((u32)p2 & 0xFFFFFu)) << 5) + l4];
        const float4 v3 = *(const float4*)&x[(((size_t)((u32)p3 & 0xFFFFFu)) << 5) + l4];
        const float a0 = __uint_as_float((u32)(p0 >> 32));
        const float a1 = __uint_as_float((u32)(p1 >> 32));
        const float a2 = __uint_as_float((u32)(p2 >> 32));
        const float a3 = __uint_as_float((u32)(p3 >> 32));
        ax = fmaf(a0, v0.x, ax); ay = fmaf(a0, v0.y, ay); az = fmaf(a0, v0.z, az); aw = fmaf(a0, v0.w, aw);
        ax = fmaf(a1, v1.x, ax); ay = fmaf(a1, v1.y, ay); az = fmaf(a1, v1.z, az); aw = fmaf(a1, v1.w, aw);
        ax = fmaf(a2, v2.x, ax); ay = fmaf(a2, v2.y, ay); az = fmaf(a2, v2.z, az); aw = fmaf(a2, v2.w, aw);
        ax = fmaf(a3, v3.x, ax); ay = fmaf(a3, v3.y, ay); az = fmaf(a3, v3.z, az); aw = fmaf(a3, v3.w, aw);
    }
    for (; k < e; ++k) {
        const u64 p = csr[k];
        const float4 v = *(const float4*)&x[(((size_t)((u32)p & 0xFFFFFu)) << 5) + l4];
        const float a = __uint_as_float((u32)(p >> 32));
        ax = fmaf(a, v.x, ax); ay = fmaf(a, v.y, ay); az = fmaf(a, v.z, az); aw = fmaf(a, v.w, aw);
    }
    float4 r; r.x = ax; r.y = ay; r.z = az; r.w = aw;
    *(float4*)&out[((size_t)gid << 5) + l4] = r;
}

// ---------- fallback (generality): direct atomic scatter ----------
__global__ void fallback_scatter(const int* __restrict__ ei, const float* __restrict__ attr,
                                 const float* __restrict__ x, float* __restrict__ out, int E) {
    const long long total = (long long)E * D_FEAT;
    const long long stride = (long long)gridDim.x * blockDim.x;
    for (long long i = (long long)blockIdx.x * blockDim.x + threadIdx.x; i < total; i += stride) {
        const int e = (int)(i >> 5);
        const int d = (int)(i & 31);
        atomicAdd(&out[((long long)ei[e] << 5) + d],
                  attr[e] * x[((long long)ei[E + e] << 5) + d]);
    }
}

extern "C" void kernel_launch(void* const* d_in, const int* in_sizes, int n_in,
                              void* d_out, int out_size, void* d_ws, size_t ws_size,
                              hipStream_t stream) {
    const int* edge_index = (const int*)d_in[0];    // [2, E] int32
    const float* edge_attr = (const float*)d_in[1]; // [E] f32
    const float* x = (const float*)d_in[2];         // [N, 32] f32
    float* out = (float*)d_out;                     // [N, 32] f32

    const int E = in_sizes[1];
    const int N = in_sizes[2] / D_FEAT;
    const int NB = (N + NPB - 1) >> BSHIFT;

    // Workspace layout (256-B aligned sections)
    char* ws = (char*)d_ws;
    int* btot = (int*)ws;                                              // NB*PAD
    size_t o1 = (((size_t)NB * PAD * 4) + 255) & ~(size_t)255;
    int* bbase = (int*)(ws + o1);                                      // NB+1
    size_t o2 = (o1 + ((size_t)(NB + 1) * 4) + 255) & ~(size_t)255;
    int* rel = (int*)(ws + o2);                                        // NBLK*NB
    size_t o3 = (o2 + ((size_t)NBLK * NB * 4) + 255) & ~(size_t)255;
    int* node_off = (int*)(ws + o3);                                   // N+1
    size_t o4 = (o3 + ((size_t)(N + 1) * 4) + 255) & ~(size_t)255;
    u64* bufA = (u64*)(ws + o4);                                       // E
    size_t o5 = (o4 + ((size_t)E * 8) + 255) & ~(size_t)255;
    u64* bufB = (u64*)(ws + o5);                                       // E
    size_t need = o5 + (size_t)E * 8;

    if (NB > NB_MAX || N > (1 << 20) || need > ws_size) {
        hipMemsetAsync(d_out, 0, (size_t)out_size * sizeof(float), stream);
        long long total = (long long)E * D_FEAT;
        int grid = (int)((total + 255) / 256);
        if (grid > 65536) grid = 65536;
        fallback_scatter<<<grid, 256, 0, stream>>>(edge_index, edge_attr, x, out, E);
        return;
    }

    hipMemsetAsync(btot, 0, (size_t)NB * PAD * 4, stream);

    int epb = (E + NBLK - 1) / NBLK;
    epb = (epb + 3) & ~3;

    count_reserve<<<NBLK, ABLK, 0, stream>>>(edge_index, btot, rel, E, NB, epb);
    scan_totals<<<1, NB_MAX, 0, stream>>>(btot, bbase, NB);
    bin_scatter<<<NBLK, ABLK, 0, stream>>>(edge_index, edge_attr, rel, bbase, bufA, E, NB, epb);
    bucket_sort<<<NB, 512, 0, stream>>>(bufA, bufB, bbase, node_off, N, NB);

    const long long gthreads = (long long)N * 8;
    csr_gather<<<(int)((gthreads + 255) / 256), 256, 0, stream>>>(bufB, node_off, x, out, N);
}